// Round 13
// baseline (1577.769 us; speedup 1.0000x reference)
//
#include <hip/hip_runtime.h>

typedef __attribute__((ext_vector_type(8))) short bf16x8;
typedef __attribute__((ext_vector_type(4))) float f32x4;

__device__ __forceinline__ unsigned short f2bf(float f) {
    unsigned u = __float_as_uint(f);
    unsigned r = (u + 0x7FFFu + ((u >> 16) & 1u)) >> 16;   // RNE
    return (unsigned short)r;
}

__device__ __forceinline__ void gload16(const unsigned short* g, unsigned short* l) {
    __builtin_amdgcn_global_load_lds((const __attribute__((address_space(1))) void*)g,
                                     (__attribute__((address_space(3))) void*)l, 16, 0, 0);
}

#define BARRIER() do { asm volatile("" ::: "memory"); __builtin_amdgcn_s_barrier(); asm volatile("" ::: "memory"); } while (0)

// ---------------- fused prep: conv_x + conv_c + c2 + packed-init + done-init ----------------
__global__ void prep_kernel(const float* __restrict__ x, unsigned short* __restrict__ xb,
                            const float* __restrict__ c, unsigned short* __restrict__ cb,
                            float* __restrict__ c2, unsigned long long* __restrict__ packed,
                            int* __restrict__ done,
                            int total8, int nxb, int N, int D) {
    const int bid = blockIdx.x;
    const int tid = threadIdx.x;
    if (bid < nxb) {
        int i = bid * 256 + tid;
        if (i >= total8) return;
        const float4* xv = (const float4*)x;
        float4 a = xv[(size_t)i * 2];
        float4 b = xv[(size_t)i * 2 + 1];
        uint4 o;
        o.x = (unsigned)f2bf(a.x) | ((unsigned)f2bf(a.y) << 16);
        o.y = (unsigned)f2bf(a.z) | ((unsigned)f2bf(a.w) << 16);
        o.z = (unsigned)f2bf(b.x) | ((unsigned)f2bf(b.y) << 16);
        o.w = (unsigned)f2bf(b.z) | ((unsigned)f2bf(b.w) << 16);
        ((uint4*)xb)[i] = o;
        return;
    }
    const int k = bid - nxb;
    const float4 v = ((const float4*)(c + (long)k * D))[tid];
    uint2 o;
    o.x = (unsigned)f2bf(v.x) | ((unsigned)f2bf(v.y) << 16);
    o.y = (unsigned)f2bf(v.z) | ((unsigned)f2bf(v.w) << 16);
    ((uint2*)(cb + (long)k * D))[tid] = o;
    float s = v.x * v.x + v.y * v.y + v.z * v.z + v.w * v.w;
    #pragma unroll
    for (int d = 1; d < 64; d <<= 1) s += __shfl_xor(s, d, 64);
    __shared__ float wsum[4];
    int lane = tid & 63, w = tid >> 6;
    if (lane == 0) wsum[w] = s;
    __syncthreads();
    if (tid == 0) { c2[k] = wsum[0] + wsum[1] + wsum[2] + wsum[3]; done[k] = 0; }
    int gid = k * 256 + tid;
    if (gid < N) packed[gid] = ~0ull;
}

// ------------- GEMM + argmin (verbatim ring-of-4, known 43.2us) -------------
__global__ void __launch_bounds__(512, 2)
gemm_argmin_kernel(const unsigned short* __restrict__ Xb,
                   const unsigned short* __restrict__ Cb,
                   const float* __restrict__ c2,
                   unsigned long long* __restrict__ packed,
                   int D, int nt) {
    __shared__ unsigned short sh[65536];       // 128 KiB
    const int tid  = threadIdx.x;
    const int lane = tid & 63;
    const int w    = tid >> 6;
    const int wr   = w >> 2;
    const int wc   = w & 3;
    const long rowbase = (long)blockIdx.x * 256;
    const int  colbase = blockIdx.y * 256;
    const int fr = lane & 15;
    const int g  = lane >> 4;

    const int c0 = tid, c1 = 512 + tid;
    const unsigned short* gA0 = Xb + (rowbase + (c0 >> 2)) * D + (c0 & 3) * 8;
    const unsigned short* gA1 = Xb + (rowbase + (c1 >> 2)) * D + (c1 & 3) * 8;
    const unsigned short* gB0 = Cb + ((long)colbase + (c0 >> 2)) * D + (c0 & 3) * 8;
    const unsigned short* gB1 = Cb + ((long)colbase + (c1 >> 2)) * D + (c1 & 3) * 8;

    f32x4 acc[8][4] = {};
    bf16x8 a[8], b[4];

    auto stage = [&](int kt) {
        const int s = (kt & 3) * 8192;
        const long ko = (long)kt * 32;
        gload16(gA0 + ko, sh + s + c0 * 8);
        gload16(gA1 + ko, sh + s + c1 * 8);
        gload16(gB0 + ko, sh + 32768 + s + c0 * 8);
        gload16(gB1 + ko, sh + 32768 + s + c1 * 8);
    };

    stage(0); stage(1); stage(2);
    asm volatile("s_waitcnt vmcnt(8)" ::: "memory");
    BARRIER();

    for (int t = 0; t < nt; ++t) {
        const int sb = (t & 3) * 8192;
        if (t + 3 < nt) stage(t + 3);
        const int ar = sb + (wr * 128 + fr) * 32 + g * 8;
        #pragma unroll
        for (int m = 0; m < 8; ++m) a[m] = *(const bf16x8*)&sh[ar + m * 512];
        const int br = 32768 + sb + (wc * 64 + fr) * 32 + g * 8;
        #pragma unroll
        for (int n = 0; n < 4; ++n) b[n] = *(const bf16x8*)&sh[br + n * 512];
        asm volatile("s_waitcnt vmcnt(8) lgkmcnt(0)" ::: "memory");
        BARRIER();
        __builtin_amdgcn_s_setprio(1);
        #pragma unroll
        for (int m = 0; m < 8; ++m)
            #pragma unroll
            for (int n = 0; n < 4; ++n)
                acc[m][n] = __builtin_amdgcn_mfma_f32_16x16x32_bf16(a[m], b[n], acc[m][n], 0, 0, 0);
        __builtin_amdgcn_s_setprio(0);
    }

    float c2v[4];
    int   kcol[4];
    #pragma unroll
    for (int n = 0; n < 4; ++n) {
        kcol[n] = colbase + wc * 64 + n * 16 + fr;
        c2v[n]  = c2[kcol[n]];
    }
    #pragma unroll
    for (int m = 0; m < 8; ++m) {
        #pragma unroll
        for (int reg = 0; reg < 4; ++reg) {
            unsigned long long best = ~0ull;
            #pragma unroll
            for (int n = 0; n < 4; ++n) {
                float score = c2v[n] - 2.0f * acc[m][n][reg];
                unsigned u = __float_as_uint(score);
                u ^= (u >> 31) ? 0xFFFFFFFFu : 0x80000000u;   // order-preserving map
                unsigned long long cand = ((unsigned long long)u << 32) | (unsigned)kcol[n];
                best = cand < best ? cand : best;
            }
            #pragma unroll
            for (int s = 1; s < 16; s <<= 1) {
                unsigned long long other = __shfl_xor(best, s, 64);
                best = other < best ? other : best;
            }
            if (fr == 0) {
                long row = rowbase + wr * 128 + m * 16 + g * 4 + reg;
                atomicMin(&packed[row], best);   // min is order-independent -> deterministic
            }
        }
    }
}

// ---------------- segmented sum + fused finalize (S=4, MLP-8 gather) ----------------
// grid (K, 4); block 1024.  Each (k,s) block: ballot-compacted index list
// (deterministic), MLP-8 gather (8 in-flight HBM loads/thread), fixed-order
// reduce -> partial[k][s][D] + pcount.  Then release-fence + atomicAdd ticket;
// the 4th arriver for cluster k acquires and finalizes (fixed-order sum of the
// 4 partials -> bitwise-identical output regardless of which block runs it).
__global__ void segsum_kernel(const unsigned long long* __restrict__ packed,
                              const float* __restrict__ emb,
                              const float* __restrict__ centers,
                              const int* __restrict__ cnt,
                              float* __restrict__ partial,
                              int* __restrict__ pcount,
                              int* __restrict__ done,
                              float* __restrict__ out,
                              int N, int D) {
    const int k   = blockIdx.x;
    const int s   = blockIdx.y;
    const int tid = threadIdx.x;
    const int grp = tid >> 8;
    const int ct  = tid & 255;
    const int lane = tid & 63, w = tid >> 6;

    __shared__ int idxbuf[4096];
    __shared__ int cnts[16];
    __shared__ float4 red[4][256];
    __shared__ int ticket;

    const int slice = N >> 2;             // 4096
    const int base0 = s * slice;
    int total = 0;
    for (int base = base0; base < base0 + slice; base += 1024) {
        const int n = base + tid;
        const bool m = ((unsigned)(packed[n] & 0xFFFFFFFFull) == (unsigned)k);
        const unsigned long long bal = __ballot(m);
        if (lane == 0) cnts[w] = (int)__popcll(bal);
        __syncthreads();
        int myoff = total, run = total;
        #pragma unroll
        for (int w2 = 0; w2 < 16; ++w2) {
            if (w2 == w) myoff = run;
            run += cnts[w2];
        }
        if (m) idxbuf[myoff + (int)__popcll(bal & ((1ull << lane) - 1ull))] = n;
        total = run;
        __syncthreads();
    }

    const long ctoff = (long)ct * 4;
    float4 a0 = {0,0,0,0}, a1 = {0,0,0,0}, a2 = {0,0,0,0}, a3 = {0,0,0,0};
    float4 a4 = {0,0,0,0}, a5 = {0,0,0,0}, a6 = {0,0,0,0}, a7 = {0,0,0,0};
    int j = grp;
    for (; j + 28 < total; j += 32) {
        const int r0 = idxbuf[j],      r1 = idxbuf[j + 4],  r2 = idxbuf[j + 8],  r3 = idxbuf[j + 12];
        const int r4 = idxbuf[j + 16], r5 = idxbuf[j + 20], r6 = idxbuf[j + 24], r7 = idxbuf[j + 28];
        const float4 v0 = *(const float4*)(emb + (long)r0 * D + ctoff);
        const float4 v1 = *(const float4*)(emb + (long)r1 * D + ctoff);
        const float4 v2 = *(const float4*)(emb + (long)r2 * D + ctoff);
        const float4 v3 = *(const float4*)(emb + (long)r3 * D + ctoff);
        const float4 v4 = *(const float4*)(emb + (long)r4 * D + ctoff);
        const float4 v5 = *(const float4*)(emb + (long)r5 * D + ctoff);
        const float4 v6 = *(const float4*)(emb + (long)r6 * D + ctoff);
        const float4 v7 = *(const float4*)(emb + (long)r7 * D + ctoff);
        a0.x += v0.x; a0.y += v0.y; a0.z += v0.z; a0.w += v0.w;
        a1.x += v1.x; a1.y += v1.y; a1.z += v1.z; a1.w += v1.w;
        a2.x += v2.x; a2.y += v2.y; a2.z += v2.z; a2.w += v2.w;
        a3.x += v3.x; a3.y += v3.y; a3.z += v3.z; a3.w += v3.w;
        a4.x += v4.x; a4.y += v4.y; a4.z += v4.z; a4.w += v4.w;
        a5.x += v5.x; a5.y += v5.y; a5.z += v5.z; a5.w += v5.w;
        a6.x += v6.x; a6.y += v6.y; a6.z += v6.z; a6.w += v6.w;
        a7.x += v7.x; a7.y += v7.y; a7.z += v7.z; a7.w += v7.w;
    }
    for (; j < total; j += 4) {
        const float4 v = *(const float4*)(emb + (long)idxbuf[j] * D + ctoff);
        a0.x += v.x; a0.y += v.y; a0.z += v.z; a0.w += v.w;
    }
    float4 acc;
    acc.x = ((a0.x + a1.x) + (a2.x + a3.x)) + ((a4.x + a5.x) + (a6.x + a7.x));
    acc.y = ((a0.y + a1.y) + (a2.y + a3.y)) + ((a4.y + a5.y) + (a6.y + a7.y));
    acc.z = ((a0.z + a1.z) + (a2.z + a3.z)) + ((a4.z + a5.z) + (a6.z + a7.z));
    acc.w = ((a0.w + a1.w) + (a2.w + a3.w)) + ((a4.w + a5.w) + (a6.w + a7.w));

    red[grp][ct] = acc;
    __syncthreads();
    if (grp == 0) {
        float4 r = red[0][ct];
        #pragma unroll
        for (int q = 1; q < 4; ++q) {
            const float4 v = red[q][ct];
            r.x += v.x; r.y += v.y; r.z += v.z; r.w += v.w;
        }
        *(float4*)(partial + ((long)(k * 4 + s)) * D + ctoff) = r;
        if (ct == 0) pcount[k * 4 + s] = total;
    }
    __syncthreads();

    // ---- last-block-done finalize (release/acquire via device-scope atomic) ----
    __threadfence();                               // release: partial+pcount visible
    if (tid == 0) ticket = atomicAdd(&done[k], 1);
    __syncthreads();
    if (ticket != 3) return;
    __threadfence();                               // acquire: see other blocks' writes

    float4 facc = {0.f, 0.f, 0.f, 0.f};
    if (grp == 0) {
        #pragma unroll
        for (int q = 0; q < 4; ++q) {              // fixed order -> deterministic
            const float4 p = *(const float4*)(partial + ((long)(k * 4 + q)) * D + ctoff);
            facc.x += p.x; facc.y += p.y; facc.z += p.z; facc.w += p.w;
        }
        const int mtot = pcount[k * 4 + 0] + pcount[k * 4 + 1] + pcount[k * 4 + 2] + pcount[k * 4 + 3];
        const float4 cv = *(const float4*)(centers + (long)k * D + ctoff);
        float4 o;
        if (mtot > 0) {
            float ccn = 0.5f * (float)cnt[k] + 0.5f * (float)mtot;
            float lr  = 1.0f / (ccn + 1.0f);
            float im  = 1.0f / (float)mtot;
            float om  = 1.0f - lr;
            o.x = om * cv.x + lr * (facc.x * im);
            o.y = om * cv.y + lr * (facc.y * im);
            o.z = om * cv.z + lr * (facc.z * im);
            o.w = om * cv.w + lr * (facc.w * im);
        } else {
            o = cv;
        }
        *(float4*)(out + (long)k * D + ctoff) = o;
    }
}

// ---------------- launch ----------------

extern "C" void kernel_launch(void* const* d_in, const int* in_sizes, int n_in,
                              void* d_out, int out_size, void* d_ws, size_t ws_size,
                              hipStream_t stream) {
    const float* emb = (const float*)d_in[0];
    const float* cen = (const float*)d_in[1];
    const int*   cnt = (const int*)d_in[2];
    float* out = (float*)d_out;
    const int K = in_sizes[2];
    const int D = in_sizes[1] / K;      // 1024
    const int N = in_sizes[0] / D;      // 16384

    char* ws = (char*)d_ws;
    size_t xb_bytes = (size_t)N * D * 2;            // 32 MB
    size_t cb_bytes = (size_t)K * D * 2;            // 2 MB
    unsigned short* Xb = (unsigned short*)ws;
    unsigned short* Cb = (unsigned short*)(ws + xb_bytes);
    float* c2 = (float*)(ws + xb_bytes + cb_bytes);
    unsigned long long* packed = (unsigned long long*)(ws + xb_bytes + cb_bytes + (size_t)K * 4);
    int* pcount = (int*)(ws + xb_bytes + cb_bytes + (size_t)K * 4 + (size_t)N * 8);
    int* done   = (int*)(ws + xb_bytes + cb_bytes + (size_t)K * 4 + (size_t)N * 8 + (size_t)K * 16);
    // partial [K][4][D] fp32 = 16 MB aliases the Xb region (dead after gemm).
    float* partial = (float*)ws;

    const int total8 = N * D / 8;                   // 2M
    const int nxb = (total8 + 255) / 256;           // 8192
    prep_kernel<<<dim3(nxb + K), dim3(256), 0, stream>>>(emb, Xb, cen, Cb, c2, packed, done, total8, nxb, N, D);
    gemm_argmin_kernel<<<dim3(N / 256, K / 256), dim3(512), 0, stream>>>(Xb, Cb, c2, packed, D, D / 32);
    segsum_kernel<<<dim3(K, 4), dim3(1024), 0, stream>>>(packed, emb, cen, cnt, partial, pcount, done, out, N, D);
}

// Round 14
// 115.798 us; speedup vs baseline: 13.6252x; 13.6252x over previous
//
#include <hip/hip_runtime.h>

typedef __attribute__((ext_vector_type(8))) short bf16x8;
typedef __attribute__((ext_vector_type(4))) float f32x4;

__device__ __forceinline__ unsigned short f2bf(float f) {
    unsigned u = __float_as_uint(f);
    unsigned r = (u + 0x7FFFu + ((u >> 16) & 1u)) >> 16;   // RNE
    return (unsigned short)r;
}

__device__ __forceinline__ void gload16(const unsigned short* g, unsigned short* l) {
    __builtin_amdgcn_global_load_lds((const __attribute__((address_space(1))) void*)g,
                                     (__attribute__((address_space(3))) void*)l, 16, 0, 0);
}

#define BARRIER() do { asm volatile("" ::: "memory"); __builtin_amdgcn_s_barrier(); asm volatile("" ::: "memory"); } while (0)

// ---------------- fused prep: conv_x + conv_c + c2 + packed-init ----------------
__global__ void prep_kernel(const float* __restrict__ x, unsigned short* __restrict__ xb,
                            const float* __restrict__ c, unsigned short* __restrict__ cb,
                            float* __restrict__ c2, unsigned long long* __restrict__ packed,
                            int total8, int nxb, int N, int D) {
    const int bid = blockIdx.x;
    const int tid = threadIdx.x;
    if (bid < nxb) {
        int i = bid * 256 + tid;
        if (i >= total8) return;
        const float4* xv = (const float4*)x;
        float4 a = xv[(size_t)i * 2];
        float4 b = xv[(size_t)i * 2 + 1];
        uint4 o;
        o.x = (unsigned)f2bf(a.x) | ((unsigned)f2bf(a.y) << 16);
        o.y = (unsigned)f2bf(a.z) | ((unsigned)f2bf(a.w) << 16);
        o.z = (unsigned)f2bf(b.x) | ((unsigned)f2bf(b.y) << 16);
        o.w = (unsigned)f2bf(b.z) | ((unsigned)f2bf(b.w) << 16);
        ((uint4*)xb)[i] = o;
        return;
    }
    const int k = bid - nxb;
    const float4 v = ((const float4*)(c + (long)k * D))[tid];
    uint2 o;
    o.x = (unsigned)f2bf(v.x) | ((unsigned)f2bf(v.y) << 16);
    o.y = (unsigned)f2bf(v.z) | ((unsigned)f2bf(v.w) << 16);
    ((uint2*)(cb + (long)k * D))[tid] = o;
    float s = v.x * v.x + v.y * v.y + v.z * v.z + v.w * v.w;
    #pragma unroll
    for (int d = 1; d < 64; d <<= 1) s += __shfl_xor(s, d, 64);
    __shared__ float wsum[4];
    int lane = tid & 63, w = tid >> 6;
    if (lane == 0) wsum[w] = s;
    __syncthreads();
    if (tid == 0) c2[k] = wsum[0] + wsum[1] + wsum[2] + wsum[3];
    int gid = k * 256 + tid;
    if (gid < N) packed[gid] = ~0ull;
}

// ------------- GEMM + argmin (verbatim ring-of-4, known 43.2us) -------------
__global__ void __launch_bounds__(512, 2)
gemm_argmin_kernel(const unsigned short* __restrict__ Xb,
                   const unsigned short* __restrict__ Cb,
                   const float* __restrict__ c2,
                   unsigned long long* __restrict__ packed,
                   int D, int nt) {
    __shared__ unsigned short sh[65536];       // 128 KiB
    const int tid  = threadIdx.x;
    const int lane = tid & 63;
    const int w    = tid >> 6;
    const int wr   = w >> 2;
    const int wc   = w & 3;
    const long rowbase = (long)blockIdx.x * 256;
    const int  colbase = blockIdx.y * 256;
    const int fr = lane & 15;
    const int g  = lane >> 4;

    const int c0 = tid, c1 = 512 + tid;
    const unsigned short* gA0 = Xb + (rowbase + (c0 >> 2)) * D + (c0 & 3) * 8;
    const unsigned short* gA1 = Xb + (rowbase + (c1 >> 2)) * D + (c1 & 3) * 8;
    const unsigned short* gB0 = Cb + ((long)colbase + (c0 >> 2)) * D + (c0 & 3) * 8;
    const unsigned short* gB1 = Cb + ((long)colbase + (c1 >> 2)) * D + (c1 & 3) * 8;

    f32x4 acc[8][4] = {};
    bf16x8 a[8], b[4];

    auto stage = [&](int kt) {
        const int s = (kt & 3) * 8192;
        const long ko = (long)kt * 32;
        gload16(gA0 + ko, sh + s + c0 * 8);
        gload16(gA1 + ko, sh + s + c1 * 8);
        gload16(gB0 + ko, sh + 32768 + s + c0 * 8);
        gload16(gB1 + ko, sh + 32768 + s + c1 * 8);
    };

    stage(0); stage(1); stage(2);
    asm volatile("s_waitcnt vmcnt(8)" ::: "memory");
    BARRIER();

    for (int t = 0; t < nt; ++t) {
        const int sb = (t & 3) * 8192;
        if (t + 3 < nt) stage(t + 3);
        const int ar = sb + (wr * 128 + fr) * 32 + g * 8;
        #pragma unroll
        for (int m = 0; m < 8; ++m) a[m] = *(const bf16x8*)&sh[ar + m * 512];
        const int br = 32768 + sb + (wc * 64 + fr) * 32 + g * 8;
        #pragma unroll
        for (int n = 0; n < 4; ++n) b[n] = *(const bf16x8*)&sh[br + n * 512];
        asm volatile("s_waitcnt vmcnt(8) lgkmcnt(0)" ::: "memory");
        BARRIER();
        __builtin_amdgcn_s_setprio(1);
        #pragma unroll
        for (int m = 0; m < 8; ++m)
            #pragma unroll
            for (int n = 0; n < 4; ++n)
                acc[m][n] = __builtin_amdgcn_mfma_f32_16x16x32_bf16(a[m], b[n], acc[m][n], 0, 0, 0);
        __builtin_amdgcn_s_setprio(0);
    }

    float c2v[4];
    int   kcol[4];
    #pragma unroll
    for (int n = 0; n < 4; ++n) {
        kcol[n] = colbase + wc * 64 + n * 16 + fr;
        c2v[n]  = c2[kcol[n]];
    }
    #pragma unroll
    for (int m = 0; m < 8; ++m) {
        #pragma unroll
        for (int reg = 0; reg < 4; ++reg) {
            unsigned long long best = ~0ull;
            #pragma unroll
            for (int n = 0; n < 4; ++n) {
                float score = c2v[n] - 2.0f * acc[m][n][reg];
                unsigned u = __float_as_uint(score);
                u ^= (u >> 31) ? 0xFFFFFFFFu : 0x80000000u;   // order-preserving map
                unsigned long long cand = ((unsigned long long)u << 32) | (unsigned)kcol[n];
                best = cand < best ? cand : best;
            }
            #pragma unroll
            for (int s = 1; s < 16; s <<= 1) {
                unsigned long long other = __shfl_xor(best, s, 64);
                best = other < best ? other : best;
            }
            if (fr == 0) {
                long row = rowbase + wr * 128 + m * 16 + g * 4 + reg;
                atomicMin(&packed[row], best);   // min is order-independent -> deterministic
            }
        }
    }
}

// ---------------- segmented sum: sliced partials (S=4, MLP-8 gather, NO fences) ----------------
__global__ void segsum_partial_kernel(const unsigned long long* __restrict__ packed,
                                      const float* __restrict__ emb,
                                      float* __restrict__ partial,
                                      int* __restrict__ pcount,
                                      int N, int D) {
    const int k   = blockIdx.x;
    const int s   = blockIdx.y;
    const int tid = threadIdx.x;
    const int grp = tid >> 8;
    const int ct  = tid & 255;
    const int lane = tid & 63, w = tid >> 6;

    __shared__ int idxbuf[4096];
    __shared__ int cnts[16];
    __shared__ float4 red[4][256];

    const int slice = N >> 2;             // 4096
    const int base0 = s * slice;
    int total = 0;
    for (int base = base0; base < base0 + slice; base += 1024) {
        const int n = base + tid;
        const bool m = ((unsigned)(packed[n] & 0xFFFFFFFFull) == (unsigned)k);
        const unsigned long long bal = __ballot(m);
        if (lane == 0) cnts[w] = (int)__popcll(bal);
        __syncthreads();
        int myoff = total, run = total;
        #pragma unroll
        for (int w2 = 0; w2 < 16; ++w2) {
            if (w2 == w) myoff = run;
            run += cnts[w2];
        }
        if (m) idxbuf[myoff + (int)__popcll(bal & ((1ull << lane) - 1ull))] = n;
        total = run;
        __syncthreads();
    }

    const long ctoff = (long)ct * 4;
    float4 a0 = {0,0,0,0}, a1 = {0,0,0,0}, a2 = {0,0,0,0}, a3 = {0,0,0,0};
    float4 a4 = {0,0,0,0}, a5 = {0,0,0,0}, a6 = {0,0,0,0}, a7 = {0,0,0,0};
    int j = grp;
    for (; j + 28 < total; j += 32) {
        const int r0 = idxbuf[j],      r1 = idxbuf[j + 4],  r2 = idxbuf[j + 8],  r3 = idxbuf[j + 12];
        const int r4 = idxbuf[j + 16], r5 = idxbuf[j + 20], r6 = idxbuf[j + 24], r7 = idxbuf[j + 28];
        const float4 v0 = *(const float4*)(emb + (long)r0 * D + ctoff);
        const float4 v1 = *(const float4*)(emb + (long)r1 * D + ctoff);
        const float4 v2 = *(const float4*)(emb + (long)r2 * D + ctoff);
        const float4 v3 = *(const float4*)(emb + (long)r3 * D + ctoff);
        const float4 v4 = *(const float4*)(emb + (long)r4 * D + ctoff);
        const float4 v5 = *(const float4*)(emb + (long)r5 * D + ctoff);
        const float4 v6 = *(const float4*)(emb + (long)r6 * D + ctoff);
        const float4 v7 = *(const float4*)(emb + (long)r7 * D + ctoff);
        a0.x += v0.x; a0.y += v0.y; a0.z += v0.z; a0.w += v0.w;
        a1.x += v1.x; a1.y += v1.y; a1.z += v1.z; a1.w += v1.w;
        a2.x += v2.x; a2.y += v2.y; a2.z += v2.z; a2.w += v2.w;
        a3.x += v3.x; a3.y += v3.y; a3.z += v3.z; a3.w += v3.w;
        a4.x += v4.x; a4.y += v4.y; a4.z += v4.z; a4.w += v4.w;
        a5.x += v5.x; a5.y += v5.y; a5.z += v5.z; a5.w += v5.w;
        a6.x += v6.x; a6.y += v6.y; a6.z += v6.z; a6.w += v6.w;
        a7.x += v7.x; a7.y += v7.y; a7.z += v7.z; a7.w += v7.w;
    }
    for (; j < total; j += 4) {
        const float4 v = *(const float4*)(emb + (long)idxbuf[j] * D + ctoff);
        a0.x += v.x; a0.y += v.y; a0.z += v.z; a0.w += v.w;
    }
    float4 acc;
    acc.x = ((a0.x + a1.x) + (a2.x + a3.x)) + ((a4.x + a5.x) + (a6.x + a7.x));
    acc.y = ((a0.y + a1.y) + (a2.y + a3.y)) + ((a4.y + a5.y) + (a6.y + a7.y));
    acc.z = ((a0.z + a1.z) + (a2.z + a3.z)) + ((a4.z + a5.z) + (a6.z + a7.z));
    acc.w = ((a0.w + a1.w) + (a2.w + a3.w)) + ((a4.w + a5.w) + (a6.w + a7.w));

    red[grp][ct] = acc;
    __syncthreads();
    if (grp == 0) {
        float4 r = red[0][ct];
        #pragma unroll
        for (int q = 1; q < 4; ++q) {
            const float4 v = red[q][ct];
            r.x += v.x; r.y += v.y; r.z += v.z; r.w += v.w;
        }
        *(float4*)(partial + ((long)(k * 4 + s)) * D + ctoff) = r;
    }
    if (tid == 0) pcount[k * 4 + s] = total;
}

// one block per cluster: reduce 4 slice partials (fixed order) + EMA finalize
__global__ void finalize_kernel(const float* __restrict__ partial,
                                const int* __restrict__ pcount,
                                const float* __restrict__ centers,
                                const int* __restrict__ cnt,
                                float* __restrict__ out, int D) {
    const int k = blockIdx.x;
    const int ct = threadIdx.x;           // 256 threads, 4 cols each
    float4 acc = {0.f, 0.f, 0.f, 0.f};
    int mtot = 0;
    #pragma unroll
    for (int s = 0; s < 4; ++s) {
        const float4 p = *(const float4*)(partial + ((long)(k * 4 + s)) * D + ct * 4);
        acc.x += p.x; acc.y += p.y; acc.z += p.z; acc.w += p.w;
        mtot += pcount[k * 4 + s];
    }
    const float4 cv = *(const float4*)(centers + (long)k * D + ct * 4);
    float4 o;
    if (mtot > 0) {
        float ccn = 0.5f * (float)cnt[k] + 0.5f * (float)mtot;
        float lr  = 1.0f / (ccn + 1.0f);
        float im  = 1.0f / (float)mtot;
        float om  = 1.0f - lr;
        o.x = om * cv.x + lr * (acc.x * im);
        o.y = om * cv.y + lr * (acc.y * im);
        o.z = om * cv.z + lr * (acc.z * im);
        o.w = om * cv.w + lr * (acc.w * im);
    } else {
        o = cv;
    }
    *(float4*)(out + (long)k * D + ct * 4) = o;
}

// ---------------- launch ----------------

extern "C" void kernel_launch(void* const* d_in, const int* in_sizes, int n_in,
                              void* d_out, int out_size, void* d_ws, size_t ws_size,
                              hipStream_t stream) {
    const float* emb = (const float*)d_in[0];
    const float* cen = (const float*)d_in[1];
    const int*   cnt = (const int*)d_in[2];
    float* out = (float*)d_out;
    const int K = in_sizes[2];
    const int D = in_sizes[1] / K;      // 1024
    const int N = in_sizes[0] / D;      // 16384

    char* ws = (char*)d_ws;
    size_t xb_bytes = (size_t)N * D * 2;            // 32 MB
    size_t cb_bytes = (size_t)K * D * 2;            // 2 MB
    unsigned short* Xb = (unsigned short*)ws;
    unsigned short* Cb = (unsigned short*)(ws + xb_bytes);
    float* c2 = (float*)(ws + xb_bytes + cb_bytes);
    unsigned long long* packed = (unsigned long long*)(ws + xb_bytes + cb_bytes + (size_t)K * 4);
    int* pcount = (int*)(ws + xb_bytes + cb_bytes + (size_t)K * 4 + (size_t)N * 8);
    // partial [K][4][D] fp32 = 16 MB aliases the Xb region (dead after gemm).
    float* partial = (float*)ws;

    const int total8 = N * D / 8;                   // 2M
    const int nxb = (total8 + 255) / 256;           // 8192
    prep_kernel<<<dim3(nxb + K), dim3(256), 0, stream>>>(emb, Xb, cen, Cb, c2, packed, total8, nxb, N, D);
    gemm_argmin_kernel<<<dim3(N / 256, K / 256), dim3(512), 0, stream>>>(Xb, Cb, c2, packed, D, D / 32);
    segsum_partial_kernel<<<dim3(K, 4), dim3(1024), 0, stream>>>(packed, emb, partial, pcount, N, D);
    finalize_kernel<<<dim3(K), dim3(256), 0, stream>>>(partial, pcount, cen, cnt, out, D);
}

// Round 15
// 96.609 us; speedup vs baseline: 16.3315x; 1.1986x over previous
//
#include <hip/hip_runtime.h>

typedef __attribute__((ext_vector_type(8))) short bf16x8;
typedef __attribute__((ext_vector_type(4))) float f32x4;

__device__ __forceinline__ unsigned short f2bf(float f) {
    unsigned u = __float_as_uint(f);
    unsigned r = (u + 0x7FFFu + ((u >> 16) & 1u)) >> 16;   // RNE
    return (unsigned short)r;
}

__device__ __forceinline__ void gload16(const unsigned short* g, unsigned short* l) {
    __builtin_amdgcn_global_load_lds((const __attribute__((address_space(1))) void*)g,
                                     (__attribute__((address_space(3))) void*)l, 16, 0, 0);
}

#define BARRIER() do { asm volatile("" ::: "memory"); __builtin_amdgcn_s_barrier(); asm volatile("" ::: "memory"); } while (0)

// ---------------- fused prep: conv_x + conv_c + c2 + packed-init ----------------
__global__ void prep_kernel(const float* __restrict__ x, unsigned short* __restrict__ xb,
                            const float* __restrict__ c, unsigned short* __restrict__ cb,
                            float* __restrict__ c2, unsigned long long* __restrict__ packed,
                            int total8, int nxb, int N, int D) {
    const int bid = blockIdx.x;
    const int tid = threadIdx.x;
    if (bid < nxb) {
        int i = bid * 256 + tid;
        if (i >= total8) return;
        const float4* xv = (const float4*)x;
        float4 a = xv[(size_t)i * 2];
        float4 b = xv[(size_t)i * 2 + 1];
        uint4 o;
        o.x = (unsigned)f2bf(a.x) | ((unsigned)f2bf(a.y) << 16);
        o.y = (unsigned)f2bf(a.z) | ((unsigned)f2bf(a.w) << 16);
        o.z = (unsigned)f2bf(b.x) | ((unsigned)f2bf(b.y) << 16);
        o.w = (unsigned)f2bf(b.z) | ((unsigned)f2bf(b.w) << 16);
        ((uint4*)xb)[i] = o;
        return;
    }
    const int k = bid - nxb;
    const float4 v = ((const float4*)(c + (long)k * D))[tid];
    uint2 o;
    o.x = (unsigned)f2bf(v.x) | ((unsigned)f2bf(v.y) << 16);
    o.y = (unsigned)f2bf(v.z) | ((unsigned)f2bf(v.w) << 16);
    ((uint2*)(cb + (long)k * D))[tid] = o;
    float s = v.x * v.x + v.y * v.y + v.z * v.z + v.w * v.w;
    #pragma unroll
    for (int d = 1; d < 64; d <<= 1) s += __shfl_xor(s, d, 64);
    __shared__ float wsum[4];
    int lane = tid & 63, w = tid >> 6;
    if (lane == 0) wsum[w] = s;
    __syncthreads();
    if (tid == 0) c2[k] = wsum[0] + wsum[1] + wsum[2] + wsum[3];
    int gid = k * 256 + tid;
    if (gid < N) packed[gid] = ~0ull;
}

// ------------- GEMM + argmin (verbatim ring-of-4, known 43.2us) -------------
__global__ void __launch_bounds__(512, 2)
gemm_argmin_kernel(const unsigned short* __restrict__ Xb,
                   const unsigned short* __restrict__ Cb,
                   const float* __restrict__ c2,
                   unsigned long long* __restrict__ packed,
                   int D, int nt) {
    __shared__ unsigned short sh[65536];       // 128 KiB
    const int tid  = threadIdx.x;
    const int lane = tid & 63;
    const int w    = tid >> 6;
    const int wr   = w >> 2;
    const int wc   = w & 3;
    const long rowbase = (long)blockIdx.x * 256;
    const int  colbase = blockIdx.y * 256;
    const int fr = lane & 15;
    const int g  = lane >> 4;

    const int c0 = tid, c1 = 512 + tid;
    const unsigned short* gA0 = Xb + (rowbase + (c0 >> 2)) * D + (c0 & 3) * 8;
    const unsigned short* gA1 = Xb + (rowbase + (c1 >> 2)) * D + (c1 & 3) * 8;
    const unsigned short* gB0 = Cb + ((long)colbase + (c0 >> 2)) * D + (c0 & 3) * 8;
    const unsigned short* gB1 = Cb + ((long)colbase + (c1 >> 2)) * D + (c1 & 3) * 8;

    f32x4 acc[8][4] = {};
    bf16x8 a[8], b[4];

    auto stage = [&](int kt) {
        const int s = (kt & 3) * 8192;
        const long ko = (long)kt * 32;
        gload16(gA0 + ko, sh + s + c0 * 8);
        gload16(gA1 + ko, sh + s + c1 * 8);
        gload16(gB0 + ko, sh + 32768 + s + c0 * 8);
        gload16(gB1 + ko, sh + 32768 + s + c1 * 8);
    };

    stage(0); stage(1); stage(2);
    asm volatile("s_waitcnt vmcnt(8)" ::: "memory");
    BARRIER();

    for (int t = 0; t < nt; ++t) {
        const int sb = (t & 3) * 8192;
        if (t + 3 < nt) stage(t + 3);
        const int ar = sb + (wr * 128 + fr) * 32 + g * 8;
        #pragma unroll
        for (int m = 0; m < 8; ++m) a[m] = *(const bf16x8*)&sh[ar + m * 512];
        const int br = 32768 + sb + (wc * 64 + fr) * 32 + g * 8;
        #pragma unroll
        for (int n = 0; n < 4; ++n) b[n] = *(const bf16x8*)&sh[br + n * 512];
        asm volatile("s_waitcnt vmcnt(8) lgkmcnt(0)" ::: "memory");
        BARRIER();
        __builtin_amdgcn_s_setprio(1);
        #pragma unroll
        for (int m = 0; m < 8; ++m)
            #pragma unroll
            for (int n = 0; n < 4; ++n)
                acc[m][n] = __builtin_amdgcn_mfma_f32_16x16x32_bf16(a[m], b[n], acc[m][n], 0, 0, 0);
        __builtin_amdgcn_s_setprio(0);
    }

    float c2v[4];
    int   kcol[4];
    #pragma unroll
    for (int n = 0; n < 4; ++n) {
        kcol[n] = colbase + wc * 64 + n * 16 + fr;
        c2v[n]  = c2[kcol[n]];
    }
    #pragma unroll
    for (int m = 0; m < 8; ++m) {
        #pragma unroll
        for (int reg = 0; reg < 4; ++reg) {
            unsigned long long best = ~0ull;
            #pragma unroll
            for (int n = 0; n < 4; ++n) {
                float score = c2v[n] - 2.0f * acc[m][n][reg];
                unsigned u = __float_as_uint(score);
                u ^= (u >> 31) ? 0xFFFFFFFFu : 0x80000000u;   // order-preserving map
                unsigned long long cand = ((unsigned long long)u << 32) | (unsigned)kcol[n];
                best = cand < best ? cand : best;
            }
            #pragma unroll
            for (int s = 1; s < 16; s <<= 1) {
                unsigned long long other = __shfl_xor(best, s, 64);
                best = other < best ? other : best;
            }
            if (fr == 0) {
                long row = rowbase + wr * 128 + m * 16 + g * 4 + reg;
                atomicMin(&packed[row], best);   // min is order-independent -> deterministic
            }
        }
    }
}

// ---------------- segmented sum: sliced partials (S=4, MLP-4 gather) ----------------
// grid (K, 4); block 1024 = 4 row-groups x 256 col-threads.  Gather loop unrolled
// x4 with independent accumulators (fits the register budget; MLP-8 spilled at
// VGPR=36 and regressed 2.7x -- round 14).  Fixed summation order -> bitwise
// deterministic across replays.
__global__ void segsum_partial_kernel(const unsigned long long* __restrict__ packed,
                                      const float* __restrict__ emb,
                                      float* __restrict__ partial,
                                      int* __restrict__ pcount,
                                      int N, int D) {
    const int k   = blockIdx.x;
    const int s   = blockIdx.y;
    const int tid = threadIdx.x;
    const int grp = tid >> 8;
    const int ct  = tid & 255;
    const int lane = tid & 63, w = tid >> 6;

    __shared__ int idxbuf[4096];
    __shared__ int cnts[16];
    __shared__ float4 red[4][256];

    const int slice = N >> 2;             // 4096
    const int base0 = s * slice;
    int total = 0;
    for (int base = base0; base < base0 + slice; base += 1024) {
        const int n = base + tid;
        const bool m = ((unsigned)(packed[n] & 0xFFFFFFFFull) == (unsigned)k);
        const unsigned long long bal = __ballot(m);
        if (lane == 0) cnts[w] = (int)__popcll(bal);
        __syncthreads();
        int myoff = total, run = total;
        #pragma unroll
        for (int w2 = 0; w2 < 16; ++w2) {
            if (w2 == w) myoff = run;
            run += cnts[w2];
        }
        if (m) idxbuf[myoff + (int)__popcll(bal & ((1ull << lane) - 1ull))] = n;
        total = run;
        __syncthreads();
    }

    const long ctoff = (long)ct * 4;
    float4 a0 = {0.f,0.f,0.f,0.f}, a1 = {0.f,0.f,0.f,0.f};
    float4 a2 = {0.f,0.f,0.f,0.f}, a3 = {0.f,0.f,0.f,0.f};
    int j = grp;
    for (; j + 12 < total; j += 16) {
        const int r0 = idxbuf[j];
        const int r1 = idxbuf[j + 4];
        const int r2 = idxbuf[j + 8];
        const int r3 = idxbuf[j + 12];
        const float4 v0 = *(const float4*)(emb + (long)r0 * D + ctoff);
        const float4 v1 = *(const float4*)(emb + (long)r1 * D + ctoff);
        const float4 v2 = *(const float4*)(emb + (long)r2 * D + ctoff);
        const float4 v3 = *(const float4*)(emb + (long)r3 * D + ctoff);
        a0.x += v0.x; a0.y += v0.y; a0.z += v0.z; a0.w += v0.w;
        a1.x += v1.x; a1.y += v1.y; a1.z += v1.z; a1.w += v1.w;
        a2.x += v2.x; a2.y += v2.y; a2.z += v2.z; a2.w += v2.w;
        a3.x += v3.x; a3.y += v3.y; a3.z += v3.z; a3.w += v3.w;
    }
    for (; j < total; j += 4) {
        const float4 v = *(const float4*)(emb + (long)idxbuf[j] * D + ctoff);
        a0.x += v.x; a0.y += v.y; a0.z += v.z; a0.w += v.w;
    }
    float4 acc;
    acc.x = (a0.x + a1.x) + (a2.x + a3.x);
    acc.y = (a0.y + a1.y) + (a2.y + a3.y);
    acc.z = (a0.z + a1.z) + (a2.z + a3.z);
    acc.w = (a0.w + a1.w) + (a2.w + a3.w);

    red[grp][ct] = acc;
    __syncthreads();
    if (grp == 0) {
        float4 r = red[0][ct];
        #pragma unroll
        for (int q = 1; q < 4; ++q) {
            const float4 v = red[q][ct];
            r.x += v.x; r.y += v.y; r.z += v.z; r.w += v.w;
        }
        *(float4*)(partial + ((long)(k * 4 + s)) * D + ctoff) = r;
    }
    if (tid == 0) pcount[k * 4 + s] = total;
}

// one block per cluster: reduce 4 slice partials (fixed order) + EMA finalize
__global__ void finalize_kernel(const float* __restrict__ partial,
                                const int* __restrict__ pcount,
                                const float* __restrict__ centers,
                                const int* __restrict__ cnt,
                                float* __restrict__ out, int D) {
    const int k = blockIdx.x;
    const int ct = threadIdx.x;           // 256 threads, 4 cols each
    float4 acc = {0.f, 0.f, 0.f, 0.f};
    int mtot = 0;
    #pragma unroll
    for (int s = 0; s < 4; ++s) {
        const float4 p = *(const float4*)(partial + ((long)(k * 4 + s)) * D + ct * 4);
        acc.x += p.x; acc.y += p.y; acc.z += p.z; acc.w += p.w;
        mtot += pcount[k * 4 + s];
    }
    const float4 cv = *(const float4*)(centers + (long)k * D + ct * 4);
    float4 o;
    if (mtot > 0) {
        float ccn = 0.5f * (float)cnt[k] + 0.5f * (float)mtot;
        float lr  = 1.0f / (ccn + 1.0f);
        float im  = 1.0f / (float)mtot;
        float om  = 1.0f - lr;
        o.x = om * cv.x + lr * (acc.x * im);
        o.y = om * cv.y + lr * (acc.y * im);
        o.z = om * cv.z + lr * (acc.z * im);
        o.w = om * cv.w + lr * (acc.w * im);
    } else {
        o = cv;
    }
    *(float4*)(out + (long)k * D + ct * 4) = o;
}

// ---------------- launch ----------------

extern "C" void kernel_launch(void* const* d_in, const int* in_sizes, int n_in,
                              void* d_out, int out_size, void* d_ws, size_t ws_size,
                              hipStream_t stream) {
    const float* emb = (const float*)d_in[0];
    const float* cen = (const float*)d_in[1];
    const int*   cnt = (const int*)d_in[2];
    float* out = (float*)d_out;
    const int K = in_sizes[2];
    const int D = in_sizes[1] / K;      // 1024
    const int N = in_sizes[0] / D;      // 16384

    char* ws = (char*)d_ws;
    size_t xb_bytes = (size_t)N * D * 2;            // 32 MB
    size_t cb_bytes = (size_t)K * D * 2;            // 2 MB
    unsigned short* Xb = (unsigned short*)ws;
    unsigned short* Cb = (unsigned short*)(ws + xb_bytes);
    float* c2 = (float*)(ws + xb_bytes + cb_bytes);
    unsigned long long* packed = (unsigned long long*)(ws + xb_bytes + cb_bytes + (size_t)K * 4);
    int* pcount = (int*)(ws + xb_bytes + cb_bytes + (size_t)K * 4 + (size_t)N * 8);
    // partial [K][4][D] fp32 = 16 MB aliases the Xb region (dead after gemm).
    float* partial = (float*)ws;

    const int total8 = N * D / 8;                   // 2M
    const int nxb = (total8 + 255) / 256;           // 8192
    prep_kernel<<<dim3(nxb + K), dim3(256), 0, stream>>>(emb, Xb, cen, Cb, c2, packed, total8, nxb, N, D);
    gemm_argmin_kernel<<<dim3(N / 256, K / 256), dim3(512), 0, stream>>>(Xb, Cb, c2, packed, D, D / 32);
    segsum_partial_kernel<<<dim3(K, 4), dim3(1024), 0, stream>>>(packed, emb, partial, pcount, N, D);
    finalize_kernel<<<dim3(K), dim3(256), 0, stream>>>(partial, pcount, cen, cnt, out, D);
}